// Round 3
// baseline (274.166 us; speedup 1.0000x reference)
//
#include <hip/hip_runtime.h>

// TileWarping: B=4, C=16, H=512, W=960, UP=4 -> out [4, 48, 128, 240] f32.
// R2: many small single-barrier blocks for inter-block latency hiding.
//  - block = 256 threads (4 waves) <-> one 256-px segment of one (b,Y) row.
//  - stages all 16 fea_r channel-windows (256 + 2*16 guard = 288 dwords each,
//    18.4 KB) via async global_load_lds width=16; ONE __syncthreads.
//  - 8 blocks/CU (LDS-limited) = 32 waves/CU: other blocks' compute hides any
//    block's DMA drain at its barrier.
//  - k-trick: 3 disp_d variants share taps L[p..p+3]; OOB-of-image taps are
//    masked via per-variant weights; taps outside the staged window but inside
//    the image (|disp|>~14, ~0 per run) take a rare global-gather fallback.

#define NB 4
#define NC 16
#define NH 512
#define NW 960
#define TH 128
#define TW 240
#define HW (NH * NW)
#define SEG 256
#define GUARD 16
#define WIN (SEG + 2 * GUARD)    // 288 dwords per channel window
#define SLOTS (NC * WIN / 4)     // 1152 float4 slots
#define SLOTS_PER_CH (WIN / 4)   // 72

typedef const __attribute__((address_space(1))) unsigned int* gas_u32;
typedef __attribute__((address_space(3))) unsigned int* las_u32;

__device__ __forceinline__ void stage16(const float* g, float* l) {
    __builtin_amdgcn_global_load_lds((gas_u32)g, (las_u32)l, 16, 0, 0);
}

__global__ __launch_bounds__(256, 8) void tile_warp_kernel(
    const float* __restrict__ tp,   // [B,3,128,240]
    const float* __restrict__ fl,   // [B,16,512,960]
    const float* __restrict__ fr,   // [B,16,512,960]
    float* __restrict__ out)        // [B,48,128,240]
{
    const int t = threadIdx.x;      // 0..255
    const int s = blockIdx.x;       // segment 0..3
    const int Y = blockIdx.y;       // 0..511
    const int b = blockIdx.z;       // 0..3
    const int base = s * SEG;
    const int X = base + t;         // global column (may be >=960 for seg 3)

    __shared__ float lds[NC * WIN]; // 18432 B

    const float* frrow = fr + (size_t)(b * NC) * HW + (size_t)Y * NW;

    // ---- async DMA staging: slot -> (channel, window offset) ----
#pragma unroll
    for (int k = 0; k < 4; ++k) {
        const int slot = t + 256 * k;
        const int c = slot / SLOTS_PER_CH;
        const int off = slot - c * SLOTS_PER_CH;
        int gx = base - GUARD + 4 * off;
        gx = min(max(gx, 0), NW - 4);          // clamp keeps loads in-row
        stage16(frrow + (size_t)c * HW + gx, &lds[4 * slot]);
    }
    if (t < SLOTS - 1024) {                    // k=4 tail: waves 0-1 only
        const int slot = t + 1024;
        const int c = slot / SLOTS_PER_CH;
        const int off = slot - c * SLOTS_PER_CH;
        int gx = base - GUARD + 4 * off;
        gx = min(max(gx, 0), NW - 4);
        stage16(frrow + (size_t)c * HW + gx, &lds[4 * slot]);
    }

    // ---- per-thread setup (overlaps DMA) ----
    const int y = Y >> 2, i = Y & 3;
    const int j = X & 3;
    const int T = X >> 2;
    const int Tc = min(T, TW - 1);             // clamp for seg-3 inactive cols

    const int tpb = (b * 3 * TH + y) * TW + Tc;
    const float d   = tp[tpb];
    const float dxv = tp[tpb + TH * TW];
    const float dyv = tp[tpb + 2 * TH * TW];
    const float disp = d + ((float)i - 1.5f) * dyv + ((float)j - 1.5f) * dxv;
    const float xf  = (float)X - disp;         // disp_d = 0 variant
    const float x0f = floorf(xf);
    const float w1  = xf - x0f;
    const float w0  = 1.0f - w1;
    const int   x0  = (int)x0f;
    const int   p   = x0 - 1;                  // shared taps p..p+3
    const int   q   = p - base + GUARD;        // window-local tap0
    const int   qc  = min(max(q, 0), WIN - 4);
    const bool  spill = (q != qc) && (X < NW);

    // per-variant masked weights (channel-invariant)
    float w0k[3], w1k[3];
#pragma unroll
    for (int kk = 0; kk < 3; ++kk) {
        const int xa = p + 2 - kk;
        const int xb = xa + 1;
        w0k[kk] = (xa >= 0 && xa < NW) ? w0 : 0.0f;
        w1k[kk] = (xb >= 0 && xb < NW) ? w1 : 0.0f;
    }

    const float* flp = fl + (size_t)(b * NC) * HW + (size_t)Y * NW + min(X, NW - 1);

    __syncthreads();                           // single barrier: DMA drained

    float a0 = 0.f, a1 = 0.f, a2 = 0.f;
#pragma unroll
    for (int g = 0; g < 4; ++g) {
        float flv[4];
#pragma unroll
        for (int cc = 0; cc < 4; ++cc) flv[cc] = flp[(size_t)(4 * g + cc) * HW];
#pragma unroll
        for (int cc = 0; cc < 4; ++cc) {
            const float* L = &lds[(4 * g + cc) * WIN + qc];
            const float m0 = L[0], m1 = L[1], m2 = L[2], m3 = L[3];
            a0 += fabsf(flv[cc] - (m2 * w0k[0] + m3 * w1k[0]));
            a1 += fabsf(flv[cc] - (m1 * w0k[1] + m2 * w1k[1]));
            a2 += fabsf(flv[cc] - (m0 * w0k[2] + m1 * w1k[2]));
        }
    }

    // rare fallback: taps inside image but outside staged window
    if (__builtin_expect(spill, 0)) {
        a0 = a1 = a2 = 0.f;
        const int t0 = min(max(p,     0), NW - 1);
        const int t1 = min(max(p + 1, 0), NW - 1);
        const int t2 = min(max(p + 2, 0), NW - 1);
        const int t3 = min(max(p + 3, 0), NW - 1);
        for (int c = 0; c < NC; ++c) {
            const float* R = frrow + (size_t)c * HW;
            const float m0 = R[t0], m1 = R[t1], m2 = R[t2], m3 = R[t3];
            const float fv = flp[(size_t)c * HW];
            a0 += fabsf(fv - (m2 * w0k[0] + m3 * w1k[0]));
            a1 += fabsf(fv - (m1 * w0k[1] + m2 * w1k[1]));
            a2 += fabsf(fv - (m0 * w0k[2] + m1 * w1k[2]));
        }
    }

    if (X < NW) {
        const size_t ob = ((size_t)(b * 48 + i * 4 + j) * TH + y) * TW + T;
        out[ob]                        = a0;
        out[ob + 16 * (size_t)TH * TW] = a1;
        out[ob + 32 * (size_t)TH * TW] = a2;
    }
}

extern "C" void kernel_launch(void* const* d_in, const int* in_sizes, int n_in,
                              void* d_out, int out_size, void* d_ws, size_t ws_size,
                              hipStream_t stream) {
    const float* tp = (const float*)d_in[0];
    const float* fl = (const float*)d_in[1];
    const float* fr = (const float*)d_in[2];
    float* out = (float*)d_out;

    dim3 grid(4, NH, NB);   // (segments, rows, batch) = 8192 blocks
    dim3 block(256);
    tile_warp_kernel<<<grid, block, 0, stream>>>(tp, fl, fr, out);
}